// Round 1
// baseline (1836.580 us; speedup 1.0000x reference)
//
#include <hip/hip_runtime.h>
#include <stdint.h>

#define TREL 4
#define HDIM 128
#define KDIM 256
#define NOUT 384
#define MP   128

typedef __attribute__((ext_vector_type(8))) short bf16x8;
typedef __attribute__((ext_vector_type(4))) float f32x4;

__device__ __forceinline__ ushort f2bf(float f) {
  uint32_t u = __float_as_uint(f);
  u = u + 0x7FFFu + ((u >> 16) & 1u);
  return (ushort)(u >> 16);
}

__device__ __forceinline__ void gload16(void* lds, const void* g) {
  __builtin_amdgcn_global_load_lds(
      (const __attribute__((address_space(1))) uint32_t*)g,
      (__attribute__((address_space(3))) uint32_t*)lds, 16, 0, 0);
}

__device__ __forceinline__ void atomAddF(float* p, float v) {
  unsafeAtomicAdd(p, v);
}

__global__ void k_prep_x(const float4* __restrict__ x4, ushort4* __restrict__ xb4, int n4) {
  int i = blockIdx.x * blockDim.x + threadIdx.x;
  if (i < n4) {
    float4 v = x4[i];
    ushort4 o;
    o.x = f2bf(v.x); o.y = f2bf(v.y); o.z = f2bf(v.z); o.w = f2bf(v.w);
    xb4[i] = o;
  }
}

// Wt[t][n][k] = bf16(W[t][k][n]) : store B N-major so fragments read contiguous K
__global__ void k_prep_w(const float* __restrict__ W, ushort* __restrict__ wt) {
  int i = blockIdx.x * blockDim.x + threadIdx.x;
  if (i < TREL * NOUT * KDIM) {
    int k = i & (KDIM - 1);
    int tn = i >> 8;
    int n = tn % NOUT, t = tn / NOUT;
    wt[i] = f2bf(W[(t * KDIM + k) * NOUT + n]);
  }
}

__global__ void k_zero(float* __restrict__ out, int* __restrict__ deg, int N) {
  int stride = gridDim.x * blockDim.x;
  int total4 = N * 128;  // N*512 floats, 4 at a time
  for (int i = blockIdx.x * blockDim.x + threadIdx.x; i < total4; i += stride) {
    int node = i >> 7, c4 = i & 127;
    ((float4*)(out + (size_t)node * 1536))[c4] = make_float4(0.f, 0.f, 0.f, 0.f);
  }
  for (int i = blockIdx.x * blockDim.x + threadIdx.x; i < N; i += stride) deg[i] = 0;
}

__global__ void k_deg(const int* __restrict__ adj, int* __restrict__ deg, int TE) {
  int i = blockIdx.x * blockDim.x + threadIdx.x;
  if (i < TE) atomicAdd(&deg[adj[2 * i + 1]], 1);
}

// PHASE 0: full 384 cols; epilogue: atomic sum / mean-sum / max into out[:,0:128/128:256/384:512]
// PHASE 1: middle 128 cols only; epilogue: var_e = relu(m^2 - mean_agg[tgt]^2)+1e-7 -> atomic add out[:,256:384]
template <int PHASE>
__global__ __launch_bounds__(512)
void k_gemm(const ushort* __restrict__ xb, const ushort* __restrict__ wt,
            const float* __restrict__ bias, const int* __restrict__ adj,
            float* __restrict__ out, int E, int nTiles) {
  constexpr int BN = (PHASE == 0) ? NOUT : MP;
  constexpr int FN = (PHASE == 0) ? 6 : 2;      // 16-wide frags per wave in N
  constexpr int NB = BN / 128;                  // B staging rounds per K-step
  constexpr int WCOL = 16 * FN;                 // wave N span
  __shared__ __align__(16) ushort Alds[128][32];
  __shared__ __align__(16) ushort Blds[BN][32];
  __shared__ int nodes[2][128];

  const int t = blockIdx.x / nTiles;
  const int tile = blockIdx.x - t * nTiles;
  const int e0 = tile << 7;
  const int tid = threadIdx.x;

  if (tid < 256) {
    int r = tid & 127, which = tid >> 7;  // 0 = src, 1 = tgt
    int e = e0 + r;
    nodes[which][r] = (e < E) ? adj[(((size_t)t * E + e) << 1) + which] : 0;
  }
  __syncthreads();

  f32x4 acc[4][FN];
#pragma unroll
  for (int fm = 0; fm < 4; ++fm)
#pragma unroll
    for (int fn = 0; fn < FN; ++fn) acc[fm][fn] = (f32x4){0.f, 0.f, 0.f, 0.f};

  const int lane = tid & 63;
  const int wid = tid >> 6;
  const int wm = wid >> 2, wn = wid & 3;  // 2 x 4 wave grid
  const int l15 = lane & 15, l4 = lane >> 4;
  const int arow = tid >> 2;              // staging row (0..127)
  const int koff = (tid & 3) << 3;        // staging k elem offset {0,8,16,24}

  for (int ks = 0; ks < 8; ++ks) {  // K = 256, BK = 32
    {
      int node = nodes[ks >> 2][arow];  // ks<4: src half, ks>=4: tgt half
      const ushort* gA = xb + (size_t)node * HDIM + ((ks << 5) & 127) + koff;
      gload16(&Alds[arow][koff], gA);
#pragma unroll
      for (int r = 0; r < NB; ++r) {
        int nrow = (r << 7) + arow;
        int nwt = (PHASE == 0) ? nrow : (MP + nrow);
        const ushort* gB = wt + ((size_t)(t * NOUT + nwt) << 8) + (ks << 5) + koff;
        gload16(&Blds[nrow][koff], gB);
      }
    }
    __syncthreads();
    bf16x8 afr[4], bfr[FN];
#pragma unroll
    for (int fm = 0; fm < 4; ++fm)
      afr[fm] = *(const bf16x8*)&Alds[wm * 64 + fm * 16 + l15][l4 << 3];
#pragma unroll
    for (int fn = 0; fn < FN; ++fn)
      bfr[fn] = *(const bf16x8*)&Blds[wn * WCOL + fn * 16 + l15][l4 << 3];
#pragma unroll
    for (int fm = 0; fm < 4; ++fm)
#pragma unroll
      for (int fn = 0; fn < FN; ++fn)
        acc[fm][fn] = __builtin_amdgcn_mfma_f32_16x16x32_bf16(afr[fm], bfr[fn], acc[fm][fn], 0, 0, 0);
    __syncthreads();
  }

#pragma unroll
  for (int fn = 0; fn < FN; ++fn) {
    const int n = wn * WCOL + fn * 16 + l15;
    const float bv = bias[t * NOUT + ((PHASE == 0) ? n : (MP + n))];
#pragma unroll
    for (int fm = 0; fm < 4; ++fm) {
#pragma unroll
      for (int j = 0; j < 4; ++j) {
        const int r = wm * 64 + fm * 16 + (l4 << 2) + j;
        if (e0 + r < E) {
          const int node = nodes[1][r];
          float v = acc[fm][fn][j] + bv;
          v = v > 0.f ? v : 0.f;  // relu -> msg value
          size_t base = (size_t)node * 1536;
          if (PHASE == 0) {
            const int third = n >> 7, c = n & 127;
            if (third == 0)
              atomAddF(out + base + c, v);
            else if (third == 1)
              atomAddF(out + base + 128 + c, v);
            else
              atomicMax((int*)(out + base + 384 + c), __float_as_int(v));
          } else {
            const float a = out[base + 128 + n];  // finalized mean_agg[tgt]
            float var = v * v - a * a;
            var = var > 0.f ? var : 0.f;
            atomAddF(out + base + 256 + n, var + 1e-7f);
          }
        }
      }
    }
  }
}

__global__ void k_finmean(float* __restrict__ out, const int* __restrict__ deg, int N) {
  int i = blockIdx.x * blockDim.x + threadIdx.x;
  if (i < N * HDIM) {
    int node = i >> 7, c = i & 127;
    float d = (float)deg[node];
    if (d < 1.f) d = 1.f;
    size_t idx = (size_t)node * 1536 + 128 + c;
    out[idx] = out[idx] / d;
  }
}

__global__ void k_final(float* __restrict__ out, const int* __restrict__ deg, int N) {
  int node = blockIdx.x;
  if (node >= N) return;
  float d = (float)deg[node];
  float ld = logf(d + 1.0f);
  float amp = ld / 1.1515f;
  float att = 1.1515f / (ld + 1e-7f);
  size_t base = (size_t)node * 1536;
  for (int c = threadIdx.x; c < 512; c += 256) {
    float v = out[base + c];
    if (c >= 256 && c < 384) {  // varsum -> std
      v = sqrtf(v);
      out[base + c] = v;
    }
    out[base + 512 + c] = amp * v;
    out[base + 1024 + c] = att * v;
  }
}

extern "C" void kernel_launch(void* const* d_in, const int* in_sizes, int n_in,
                              void* d_out, int out_size, void* d_ws, size_t ws_size,
                              hipStream_t stream) {
  const float* x = (const float*)d_in[0];
  const float* W = (const float*)d_in[1];
  const float* b = (const float*)d_in[2];
  const int* adj = (const int*)d_in[3];
  float* out = (float*)d_out;

  const int N = in_sizes[0] / HDIM;
  const int E = in_sizes[3] / (TREL * 2);
  const int TE = TREL * E;
  const int nTiles = (E + 127) >> 7;

  ushort* xb = (ushort*)d_ws;                       // N*128 bf16 (25.6 MB)
  ushort* wt = xb + (size_t)N * HDIM;               // 4*384*256 bf16 (0.8 MB)
  int* deg = (int*)(wt + TREL * NOUT * KDIM);       // N ints (0.4 MB)

  int n4 = (N * HDIM) / 4;
  k_prep_x<<<(n4 + 255) / 256, 256, 0, stream>>>((const float4*)x, (ushort4*)xb, n4);
  k_prep_w<<<(TREL * NOUT * KDIM + 255) / 256, 256, 0, stream>>>(W, wt);
  k_zero<<<2048, 256, 0, stream>>>(out, deg, N);
  k_deg<<<(TE + 255) / 256, 256, 0, stream>>>(adj, deg, TE);
  k_gemm<0><<<TREL * nTiles, 512, 0, stream>>>(xb, wt, b, adj, out, E, nTiles);
  k_finmean<<<(N * HDIM + 255) / 256, 256, 0, stream>>>(out, deg, N);
  k_gemm<1><<<TREL * nTiles, 512, 0, stream>>>(xb, wt, b, adj, out, E, nTiles);
  k_final<<<N, 256, 0, stream>>>(out, deg, N);
}